// Round 5
// baseline (312.437 us; speedup 1.0000x reference)
//
#include <hip/hip_runtime.h>

#define NN 2048      // nodes per batch
#define FF 128       // features per node
#define KK 16        // top-K
#define INF_KEY 0xFFFFFFFFFFFFFFFFull

typedef float f32x4 __attribute__((ext_vector_type(4)));

// ---------- wave64 min-reduce via DPP (VALU pipe, no LDS/permute) ----------
__device__ __forceinline__ unsigned wave_min_u32(unsigned x) {
    int v = (int)x, t;
    t = __builtin_amdgcn_update_dpp(v, v, 0x111, 0xf, 0xf, false); // row_shr:1
    v = ((unsigned)t < (unsigned)v) ? t : v;
    t = __builtin_amdgcn_update_dpp(v, v, 0x112, 0xf, 0xf, false); // row_shr:2
    v = ((unsigned)t < (unsigned)v) ? t : v;
    t = __builtin_amdgcn_update_dpp(v, v, 0x114, 0xf, 0xf, false); // row_shr:4
    v = ((unsigned)t < (unsigned)v) ? t : v;
    t = __builtin_amdgcn_update_dpp(v, v, 0x118, 0xf, 0xf, false); // row_shr:8
    v = ((unsigned)t < (unsigned)v) ? t : v;
    t = __builtin_amdgcn_update_dpp(v, v, 0x142, 0xf, 0xf, false); // row_bcast:15
    v = ((unsigned)t < (unsigned)v) ? t : v;
    t = __builtin_amdgcn_update_dpp(v, v, 0x143, 0xf, 0xf, false); // row_bcast:31
    v = ((unsigned)t < (unsigned)v) ? t : v;
    return (unsigned)__builtin_amdgcn_readlane(v, 63);
}

// Pack xyz (first 3 of 128 features) into a compact f32x4 array in the
// workspace: 512 KB total, L2-resident, read by every scatter block.
__global__ __launch_bounds__(256) void pack_xyz(
    const float* __restrict__ nodes, f32x4* __restrict__ out, int total)
{
    const int t = blockIdx.x * 256 + threadIdx.x;
    if (t < total) {
        const float* p = nodes + (size_t)t * FF;
        out[t] = (f32x4){p[0], p[1], p[2], 0.f};
    }
}

template<bool PACKED>
__device__ __forceinline__ f32x4 load_xyz(const float* __restrict__ base, int idx) {
    if constexpr (PACKED) {
        return ((const f32x4*)base)[idx];
    } else {
        const float* p = base + (size_t)idx * FF;
        return (f32x4){p[0], p[1], p[2], 0.f};
    }
}

// Minimal scatter: bulk zeros are done by hipMemsetAsync (runtime fill path,
// 6.2 TB/s measured on this buffer). One block = 4 rows (4 waves); rows >=
// 1024 never active (tau < 1024) so grid.y = 256. Inactive blocks exit on one
// scalar load. Active waves: verified one-pass per-lane sorted top-4 queue
// (packed L2 reads, R4-verified) + 16 DPP extraction rounds (R0-verified) +
// <=16 single-float causal stores from lane 0 (R1-verified). Strict-IEEE
// non-contracted d2; key order == jax top_k (d2,index) -> absmax 0.
template<bool PACKED>
__global__ __launch_bounds__(256, 8) void knn_scatter(
    const float* __restrict__ xyz,     // PACKED ? packed f32x4 base : nodes
    const int*   __restrict__ T_arr,
    const int*   __restrict__ tau_arr,
    float*       __restrict__ adj)
{
    const int b    = blockIdx.x;
    const int i0   = blockIdx.y << 2;
    const int tid  = threadIdx.x;
    const int wave = tid >> 6;
    const int lane = tid & 63;

    const int tau = tau_arr[b];
    if (i0 >= tau) return;                    // memset already zeroed

    const int i = i0 + wave;
    if (i >= tau) return;                     // inactive row in active block

    const int T = T_arr[b];
    const int M = T + tau;                    // src_valid: j < M (<= 2046)
    const float* base = PACKED ? xyz + (size_t)b * NN * 4
                               : xyz + (size_t)b * NN * FF;
    float* row = adj + ((size_t)b * NN + i) * NN;

    const int g = T + i;                      // sink global index (< M always)
    const f32x4 sp = load_xyz<PACKED>(base, g);
    const float sxv = sp.x, syv = sp.y, szv = sp.z;

    // ---- one-pass build of per-lane sorted top-4 queue (L2 reads) ----
    unsigned long long q0 = INF_KEY, q1 = INF_KEY, q2 = INF_KEY, q3 = INF_KEY;
    const int S = (M + 63) >> 6;
    #pragma unroll 4
    for (int s = 0; s < S; ++s) {
        const int j = lane + (s << 6);
        if (j < M) {
            const f32x4 v = load_xyz<PACKED>(base, j);
            float dx = __fsub_rn(sxv, v.x);
            float dy = __fsub_rn(syv, v.y);
            float dz = __fsub_rn(szv, v.z);
            float d2 = __fadd_rn(__fadd_rn(__fmul_rn(dx, dx), __fmul_rn(dy, dy)),
                                 __fmul_rn(dz, dz));
            unsigned long long key =
                ((unsigned long long)__float_as_uint(d2) << 32) | (unsigned)(j + 1);
            if (key < q3) {
                q3 = key;
                unsigned long long t;
                if (q3 < q2) { t = q2; q2 = q3; q3 = t; }
                if (q2 < q1) { t = q1; q1 = q2; q2 = t; }
                if (q1 < q0) { t = q0; q0 = q1; q1 = t; }
            }
        }
    }

    // ---- 16 extraction rounds: DPP min on head d2 + ballot index resolve ----
    unsigned long long lastpop = 0;
    for (int k = 0; k < KK; ++k) {
        const unsigned hd = (unsigned)(q0 >> 32);
        const unsigned m  = wave_min_u32(hd);
        if (m == 0xFFFFFFFFu) break;          // all lanes exhausted

        const unsigned long long mask = __ballot(hd == m);
        unsigned jwin;
        if (__popcll(mask) == 1) {            // unique head d2 (common case)
            const int w = __builtin_ctzll(mask);
            jwin = (unsigned)__builtin_amdgcn_readlane((int)(unsigned)q0, w);
        } else {                              // cross-lane d2 tie (rare)
            unsigned jc = (hd == m) ? (unsigned)q0 : 0xFFFFFFFFu;
            jwin = wave_min_u32(jc);
        }
        const int j = (int)jwin - 1;

        if (lane == 0 && j < i)               // causal: scatter a single 1.0
            row[j] = 1.0f;

        if (hd == m && (unsigned)q0 == jwin) {  // pop on the winner lane
            lastpop = ((unsigned long long)m << 32) | jwin;
            q0 = q1; q1 = q2; q2 = q3; q3 = INF_KEY;
            if (q0 == INF_KEY) {              // rare: >4 global hits this lane
                unsigned long long best = INF_KEY;
                for (int s2 = 0; s2 < S; ++s2) {
                    const int jj = lane + (s2 << 6);
                    if (jj < M) {
                        const f32x4 v = load_xyz<PACKED>(base, jj);
                        float dx = __fsub_rn(sxv, v.x);
                        float dy = __fsub_rn(syv, v.y);
                        float dz = __fsub_rn(szv, v.z);
                        float d2 = __fadd_rn(
                            __fadd_rn(__fmul_rn(dx, dx), __fmul_rn(dy, dy)),
                            __fmul_rn(dz, dz));
                        unsigned long long kk =
                            ((unsigned long long)__float_as_uint(d2) << 32)
                            | (unsigned)(jj + 1);
                        if (kk > lastpop && kk < best) best = kk;
                    }
                }
                q0 = best;
            }
        }
    }
}

extern "C" void kernel_launch(void* const* d_in, const int* in_sizes, int n_in,
                              void* d_out, int out_size, void* d_ws, size_t ws_size,
                              hipStream_t stream) {
    const float* nodes = (const float*)d_in[0];
    const int*   T     = (const int*)d_in[1];
    const int*   taus  = (const int*)d_in[2];
    float*       adj   = (float*)d_out;
    const int B = in_sizes[1];               // T has B elements (16)

    // 1) bulk zero via the runtime fill path (graph-captures as memset node;
    //    fillBufferAligned sustains 6.2 TB/s on this very buffer)
    const size_t out_bytes = (size_t)B * NN * NN * sizeof(float);
    hipMemsetAsync(adj, 0, out_bytes, stream);

    // 2) sparse top-K scatter; only rows < 1024 can be active (tau < 1024)
    dim3 grid(B, 1024 / 4);                  // 16 x 256 blocks, 256 thr each
    const size_t need = (size_t)B * NN * sizeof(f32x4);
    if (d_ws != nullptr && ws_size >= need) {
        const int total = B * NN;
        pack_xyz<<<dim3((total + 255) / 256), dim3(256), 0, stream>>>(
            nodes, (f32x4*)d_ws, total);
        knn_scatter<true><<<grid, dim3(256), 0, stream>>>(
            (const float*)d_ws, T, taus, adj);
    } else {
        knn_scatter<false><<<grid, dim3(256), 0, stream>>>(
            nodes, T, taus, adj);
    }
}